// Round 6
// baseline (750.180 us; speedup 1.0000x reference)
//
#include <hip/hip_runtime.h>
#include <hip/hip_bf16.h>
#include <math.h>

#define NTOK 49      // window tokens (7x7)
#define DIMC 128     // channels
#define NHEAD 4
#define HDIM 32
#define HSZ (NTOK*HDIM)   // 1568 elems per head plane
#define OPITCH 136        // o row pitch in shorts (272B = 68 dwords; 68%32=4 -> 2-way max)

typedef __attribute__((ext_vector_type(8))) short bf16x8;  // 8 bf16 in 4 VGPRs
typedef __attribute__((ext_vector_type(4))) float f32x4;   // MFMA C/D frag

static constexpr float SCALE = 0.17677669529663687f; // 32^-0.5

// fp32 -> bf16 (RNE)
__device__ __forceinline__ unsigned short f2bf(float f) {
    unsigned u = __float_as_uint(f);
    unsigned r = u + 0x7FFFu + ((u >> 16) & 1u);
    return (unsigned short)(r >> 16);
}
// bf16 -> fp32
__device__ __forceinline__ float bf2f(unsigned short s) {
    return __uint_as_float(((unsigned)s) << 16);
}

__device__ __forceinline__ bf16x8 cvt8(float4 lo, float4 hi) {
    bf16x8 v;
    v[0] = (short)f2bf(lo.x); v[1] = (short)f2bf(lo.y);
    v[2] = (short)f2bf(lo.z); v[3] = (short)f2bf(lo.w);
    v[4] = (short)f2bf(hi.x); v[5] = (short)f2bf(hi.y);
    v[6] = (short)f2bf(hi.z); v[7] = (short)f2bf(hi.w);
    return v;
}

// LDS plan (50176 B total):
//   q_lds : f32  [4][49][32]  bytes [0, 25088)      live through phase 2
//   k_s   : bf16 [4][49][32]  bytes [25088, 37632)  XOR-swizzled d^(r&24); dead after kreg preload
//   v_s   : bf16 [4][49][32]  bytes [37632, 50176)  dead after vreg preload
//   o_s   : bf16 [49][OPITCH] aliases k_s (+392 shorts of v_s head-0 rows), written
//           only after the preload barrier. o is bf16-rounded anyway for phase-3 MFMA,
//           so bf16 storage is numerically identical to round-3's f32 store + cvt.

__global__ __launch_bounds__(256, 2)
void winattn_fused(const float* __restrict__ x,
                   const float* __restrict__ mask,
                   const float* __restrict__ qkv_w,
                   const float* __restrict__ qkv_b,
                   const float* __restrict__ proj_w,
                   const float* __restrict__ proj_b,
                   const float* __restrict__ bias_table,
                   const int*   __restrict__ rel_index,
                   float* __restrict__ out)
{
    extern __shared__ float lds[];
    float* q_lds = lds;                               // 6272 f32
    short* k_s   = (short*)(lds + 6272);              // 6272 bf16
    short* v_s   = k_s + 6272;                        // 6272 bf16
    short* o_s   = k_s;                               // ALIASES k (safe after preload barrier)

    const int b    = blockIdx.x;
    const int tid  = threadIdx.x;
    const int lane = tid & 63;
    const int w    = tid >> 6;       // wave 0..3
    const int lrow = lane & 15;      // MFMA fragment M/N index
    const int kgrp = lane >> 4;      // MFMA k-chunk 0..3

    const float* xb = x + (size_t)b * (NTOK * DIMC);

    // ============ Phase 1 (MFMA): qkv = x @ qkv_w^T + qkv_b ============
    // wave w owns qkv cols [96w, 96w+96): 6 n-tiles x 4 m-tiles, K=128 in 4 steps.
    // A/B frag layout: row/col = lane&15, k = 32*ks + 8*(lane>>4) + e (consecutive —
    // matches m92's ds_read_b128 fragment loads). C/D (verified m89): col=lane&15,
    // row = 4*(lane>>4) + reg.
    {
        f32x4 acc[4][6];
        #pragma unroll
        for (int m = 0; m < 4; ++m)
            #pragma unroll
            for (int n = 0; n < 6; ++n)
                acc[m][n] = (f32x4){0.f, 0.f, 0.f, 0.f};

        #pragma unroll
        for (int ks = 0; ks < 4; ++ks) {
            const int k0 = 32*ks + 8*kgrp;
            bf16x8 afr[4];
            #pragma unroll
            for (int m = 0; m < 4; ++m) {
                const int r = 16*m + lrow;
                float4 lo = make_float4(0.f,0.f,0.f,0.f);
                float4 hi = make_float4(0.f,0.f,0.f,0.f);
                if (r < NTOK) {
                    lo = *reinterpret_cast<const float4*>(xb + r*DIMC + k0);
                    hi = *reinterpret_cast<const float4*>(xb + r*DIMC + k0 + 4);
                }
                afr[m] = cvt8(lo, hi);
            }
            bf16x8 bfr[6];
            #pragma unroll
            for (int n = 0; n < 6; ++n) {
                const int c = 96*w + 16*n + lrow;
                float4 lo = *reinterpret_cast<const float4*>(qkv_w + c*DIMC + k0);
                float4 hi = *reinterpret_cast<const float4*>(qkv_w + c*DIMC + k0 + 4);
                bfr[n] = cvt8(lo, hi);
            }
            #pragma unroll
            for (int m = 0; m < 4; ++m)
                #pragma unroll
                for (int n = 0; n < 6; ++n)
                    acc[m][n] = __builtin_amdgcn_mfma_f32_16x16x32_bf16(
                                    afr[m], bfr[n], acc[m][n], 0, 0, 0);
        }

        // epilogue: bias + scatter to q(f32)/k(bf16 swizzled)/v(bf16) LDS
        #pragma unroll
        for (int n = 0; n < 6; ++n) {
            const int c    = 96*w + 16*n + lrow;
            const float bi = qkv_b[c];
            const int which = c >> 7;            // 0=q 1=k 2=v
            const int h     = (c & 127) >> 5;
            const int d     = c & 31;
            #pragma unroll
            for (int m = 0; m < 4; ++m) {
                #pragma unroll
                for (int q = 0; q < 4; ++q) {
                    const int r = 16*m + 4*kgrp + q;
                    if (r < NTOK) {
                        const float val = acc[m][n][q] + bi;
                        if (which == 0)      q_lds[h*HSZ + r*HDIM + d] = val * SCALE;
                        else if (which == 1) k_s[h*HSZ + r*HDIM + (d ^ (r & 24))] = (short)f2bf(val);
                        else                 v_s[h*HSZ + r*HDIM + d] = (short)f2bf(val);
                    }
                }
            }
        }
    }
    __syncthreads();

    // ============ Phase 2: per-head attention (wave = head) — audited scaffold ============
    const int h    = w;              // 4 waves -> 4 heads
    const int mw   = b & 63;         // mask window = b % 64 (B_=4096, nW=64)
    const int jcol = lane;           // attention column owned by this lane
    const int d32  = lane & 31;      // output dim owned (lanes 32..63 duplicate)

    {
        // kreg preload: 4x ds_read_b128, swizzle-inverted.
        // stored s = d ^ (r&24); reading shorts [off, off+8) with off = (8g)^(j&24)
        // yields kv[e] = K[j][8g+e]  (XOR touches bits 3-4 only; e = bits 0-2).
        float kreg[32];
        #pragma unroll
        for (int d = 0; d < 32; ++d) kreg[d] = 0.f;
        if (jcol < NTOK) {
            const int kb = h*HSZ + jcol*HDIM;
            #pragma unroll
            for (int g = 0; g < 4; ++g) {
                const int off = (8*g) ^ (jcol & 24);
                bf16x8 kv = *reinterpret_cast<const bf16x8*>(k_s + kb + off);
                #pragma unroll
                for (int e = 0; e < 8; ++e)
                    kreg[8*g + e] = bf2f((unsigned short)kv[e]);
            }
        }
        float vreg[49];
        #pragma unroll
        for (int jj = 0; jj < NTOK; ++jj)
            vreg[jj] = bf2f((unsigned short)v_s[h*HSZ + jj*HDIM + d32]);

        // k/v now register-resident in every wave; o_s may overwrite k/v regions.
        __syncthreads();

        const float* qh   = q_lds + h*HSZ;
        const float* mrow = mask + (size_t)mw * (NTOK*NTOK);

        // software-pipelined bias+mask: bm holds row i's value entering iter i
        float bm = 0.f;
        if (jcol < NTOK)
            bm = bias_table[rel_index[jcol]*NHEAD + h] + mrow[jcol];

        for (int i = 0; i < NTOK; ++i) {
            float s0=0.f, s1=0.f, s2=0.f, s3=0.f;
            #pragma unroll
            for (int m = 0; m < 8; ++m) {
                float4 qq = *reinterpret_cast<const float4*>(qh + i*HDIM + 4*m);
                s0 += qq.x * kreg[4*m+0];
                s1 += qq.y * kreg[4*m+1];
                s2 += qq.z * kreg[4*m+2];
                s3 += qq.w * kreg[4*m+3];
            }
            const float bm_cur = bm;
            if (i + 1 < NTOK && jcol < NTOK)   // prefetch row i+1 (hidden under reduce/PV)
                bm = bias_table[rel_index[(i+1)*NTOK + jcol]*NHEAD + h]
                   + mrow[(i+1)*NTOK + jcol];

            float sv = (jcol < NTOK) ? ((s0+s1)+(s2+s3)) + bm_cur : -INFINITY;

            float mx = sv;
            #pragma unroll
            for (int off = 32; off > 0; off >>= 1) mx = fmaxf(mx, __shfl_xor(mx, off));
            float p = (jcol < NTOK) ? __expf(sv - mx) : 0.f;
            float sum = p;
            #pragma unroll
            for (int off = 32; off > 0; off >>= 1) sum += __shfl_xor(sum, off);
            const float inv = 1.0f / sum;

            const int pb = __float_as_int(p);
            float oA=0.f, oB=0.f, oC=0.f, oD=0.f;
            #pragma unroll
            for (int jj = 0; jj < 48; jj += 4) {
                oA += __int_as_float(__builtin_amdgcn_readlane(pb, jj+0)) * vreg[jj+0];
                oB += __int_as_float(__builtin_amdgcn_readlane(pb, jj+1)) * vreg[jj+1];
                oC += __int_as_float(__builtin_amdgcn_readlane(pb, jj+2)) * vreg[jj+2];
                oD += __int_as_float(__builtin_amdgcn_readlane(pb, jj+3)) * vreg[jj+3];
            }
            oA += __int_as_float(__builtin_amdgcn_readlane(pb, 48)) * vreg[48];
            const float o = ((oA+oB)+(oC+oD)) * inv;
            if (lane < 32) o_s[i*OPITCH + h*HDIM + d32] = (short)f2bf(o);
        }
    }
    __syncthreads();

    // ============ Phase 3 (MFMA): out = o @ proj_w^T + proj_b ============
    // wave w owns out cols [32w, 32w+32): 2 n-tiles x 4 m-tiles, K=128 in 4 steps.
    // o fragments load directly as bf16x8 (16B aligned: 272*r + 16*(k0/8)).
    {
        f32x4 pacc[4][2];
        #pragma unroll
        for (int m = 0; m < 4; ++m)
            #pragma unroll
            for (int n = 0; n < 2; ++n)
                pacc[m][n] = (f32x4){0.f, 0.f, 0.f, 0.f};

        #pragma unroll
        for (int ks = 0; ks < 4; ++ks) {
            const int k0 = 32*ks + 8*kgrp;
            bf16x8 afr[4];
            #pragma unroll
            for (int m = 0; m < 4; ++m) {
                const int r = 16*m + lrow;
                const int rr = (r < NTOK) ? r : 0;   // clamp; results discarded by store guard
                afr[m] = *reinterpret_cast<const bf16x8*>(o_s + rr*OPITCH + k0);
            }
            bf16x8 bfr[2];
            #pragma unroll
            for (int n = 0; n < 2; ++n) {
                const int c = 32*w + 16*n + lrow;
                float4 lo = *reinterpret_cast<const float4*>(proj_w + c*DIMC + k0);
                float4 hi = *reinterpret_cast<const float4*>(proj_w + c*DIMC + k0 + 4);
                bfr[n] = cvt8(lo, hi);
            }
            #pragma unroll
            for (int m = 0; m < 4; ++m)
                #pragma unroll
                for (int n = 0; n < 2; ++n)
                    pacc[m][n] = __builtin_amdgcn_mfma_f32_16x16x32_bf16(
                                     afr[m], bfr[n], pacc[m][n], 0, 0, 0);
        }

        float* ob = out + (size_t)b * (NTOK * DIMC);
        #pragma unroll
        for (int n = 0; n < 2; ++n) {
            const int c    = 32*w + 16*n + lrow;
            const float bi = proj_b[c];
            #pragma unroll
            for (int m = 0; m < 4; ++m) {
                #pragma unroll
                for (int q = 0; q < 4; ++q) {
                    const int r = 16*m + 4*kgrp + q;
                    if (r < NTOK) ob[r*DIMC + c] = pacc[m][n][q] + bi;
                }
            }
        }
    }
}

extern "C" void kernel_launch(void* const* d_in, const int* in_sizes, int n_in,
                              void* d_out, int out_size, void* d_ws, size_t ws_size,
                              hipStream_t stream) {
    const float* x      = (const float*)d_in[0];
    const float* mask   = (const float*)d_in[1];
    const float* qkv_w  = (const float*)d_in[2];
    const float* qkv_b  = (const float*)d_in[3];
    const float* proj_w = (const float*)d_in[4];
    const float* proj_b = (const float*)d_in[5];
    const float* tbl    = (const float*)d_in[6];
    const int*   ridx   = (const int*)d_in[7];
    float* out = (float*)d_out;

    const int B = in_sizes[0] / (NTOK * DIMC);   // 4096 windows
    const size_t shmem = 50176;                  // bytes (< 64KB: no attr call needed)

    winattn_fused<<<B, 256, shmem, stream>>>(x, mask, qkv_w, qkv_b,
                                             proj_w, proj_b, tbl, ridx, out);
}

// Round 10
// 446.364 us; speedup vs baseline: 1.6806x; 1.6806x over previous
//
#include <hip/hip_runtime.h>
#include <hip/hip_bf16.h>
#include <math.h>

#define NTOK 49      // window tokens (7x7)
#define DIMC 128     // channels
#define NHEAD 4
#define HDIM 32
#define QK_PITCH 40              // q/k row pitch (shorts): 80B rows, 16B-aligned, 2-way banks
#define Q_HEAD  (NTOK*QK_PITCH)  // 1960
#define VT_PITCH 72              // v^T row pitch (shorts): 144B rows, 16B-aligned
#define VT_HEAD (HDIM*VT_PITCH)  // 2304
#define P_PITCH 72               // P row pitch (shorts)
#define P_HEAD  (NTOK*P_PITCH)   // 3528
#define OPITCH  136              // o row pitch (shorts): 272B rows

typedef __attribute__((ext_vector_type(8))) short bf16x8;  // 8 bf16 in 4 VGPRs
typedef __attribute__((ext_vector_type(4))) float f32x4;   // MFMA C/D frag

static constexpr float SCALE = 0.17677669529663687f; // 32^-0.5

// fp32 -> bf16 (RNE) — validated numerics (round 6 pass)
__device__ __forceinline__ short f2bf(float f) {
    unsigned u = __float_as_uint(f);
    unsigned r = u + 0x7FFFu + ((u >> 16) & 1u);
    return (short)(r >> 16);
}

__device__ __forceinline__ bf16x8 cvt8(float4 lo, float4 hi) {
    bf16x8 v;
    v[0] = f2bf(lo.x); v[1] = f2bf(lo.y); v[2] = f2bf(lo.z); v[3] = f2bf(lo.w);
    v[4] = f2bf(hi.x); v[5] = f2bf(hi.y); v[6] = f2bf(hi.z); v[7] = f2bf(hi.w);
    return v;
}

// LDS plan (shorts; 39008 sh = 78016 B -> 2 blocks/CU):
//   q_s : [0,     7840)  [4][49][40] bf16, pre-scaled by SCALE
//   k_s : [7840, 15680)  [4][49][40] bf16
//   v_t : [15680,24896)  [4][32][72] bf16 TRANSPOSED (d rows, j cols); j=49..63 zeroed
//   p_s : [24896,39008)  [4][49][72] bf16 softmax probs (j=49..63 exact zeros)
//   o_s : aliases p_s    [49][136]  bf16, written after post-PV barrier
// All head-plane bases and rows are 16B-aligned for ds_read_b128.

__global__ __launch_bounds__(256, 2)
void winattn_fused(const float* __restrict__ x,
                   const float* __restrict__ mask,
                   const float* __restrict__ qkv_w,
                   const float* __restrict__ qkv_b,
                   const float* __restrict__ proj_w,
                   const float* __restrict__ proj_b,
                   const float* __restrict__ bias_table,
                   const int*   __restrict__ rel_index,
                   float* __restrict__ out)
{
    extern __shared__ short smem[];
    short* q_s = smem;                    // [4][49][40]
    short* k_s = smem + 4*Q_HEAD;         // [4][49][40]
    short* v_t = smem + 8*Q_HEAD;         // [4][32][72]
    short* p_s = v_t + 4*VT_HEAD;         // [4][49][72]
    short* o_s = p_s;                     // alias (safe after post-PV barrier)

    const int b    = blockIdx.x;
    const int tid  = threadIdx.x;
    const int lane = tid & 63;
    const int w    = tid >> 6;       // wave 0..3
    const int lrow = lane & 15;      // MFMA fragment M/N index
    const int kgrp = lane >> 4;      // MFMA k-chunk 0..3

    const float* xb = x + (size_t)b * (NTOK * DIMC);

    // ============ Phase 1 (MFMA, validated r6): qkv = x @ qkv_w^T + qkv_b ============
    // A/B frag: row/col = lane&15, k = 8*(lane>>4)+e contiguous.
    // C/D frag: col = lane&15, row = 4*(lane>>4) + reg.
    {
        f32x4 acc[4][6];
        #pragma unroll
        for (int m = 0; m < 4; ++m)
            #pragma unroll
            for (int n = 0; n < 6; ++n)
                acc[m][n] = (f32x4){0.f, 0.f, 0.f, 0.f};

        #pragma unroll
        for (int ks = 0; ks < 4; ++ks) {
            const int k0 = 32*ks + 8*kgrp;
            bf16x8 afr[4];
            #pragma unroll
            for (int m = 0; m < 4; ++m) {
                const int r = 16*m + lrow;
                float4 lo = make_float4(0.f,0.f,0.f,0.f);
                float4 hi = make_float4(0.f,0.f,0.f,0.f);
                if (r < NTOK) {
                    lo = *reinterpret_cast<const float4*>(xb + r*DIMC + k0);
                    hi = *reinterpret_cast<const float4*>(xb + r*DIMC + k0 + 4);
                }
                afr[m] = cvt8(lo, hi);
            }
            bf16x8 bfr[6];
            #pragma unroll
            for (int n = 0; n < 6; ++n) {
                const int c = 96*w + 16*n + lrow;
                float4 lo = *reinterpret_cast<const float4*>(qkv_w + c*DIMC + k0);
                float4 hi = *reinterpret_cast<const float4*>(qkv_w + c*DIMC + k0 + 4);
                bfr[n] = cvt8(lo, hi);
            }
            #pragma unroll
            for (int m = 0; m < 4; ++m)
                #pragma unroll
                for (int n = 0; n < 6; ++n)
                    acc[m][n] = __builtin_amdgcn_mfma_f32_16x16x32_bf16(
                                    afr[m], bfr[n], acc[m][n], 0, 0, 0);
        }

        // epilogue: bias + scatter q/k (row-major) and v (TRANSPOSED, zero-padded rows 49..63)
        #pragma unroll
        for (int n = 0; n < 6; ++n) {
            const int c    = 96*w + 16*n + lrow;
            const float bi = qkv_b[c];
            const int which = c >> 7;            // 0=q 1=k 2=v
            const int hh    = (c & 127) >> 5;
            const int d     = c & 31;
            #pragma unroll
            for (int m = 0; m < 4; ++m) {
                #pragma unroll
                for (int q = 0; q < 4; ++q) {
                    const int r = 16*m + 4*kgrp + q;   // 0..63
                    const float val = acc[m][n][q] + bi;
                    if (which == 0) {
                        if (r < NTOK) q_s[hh*Q_HEAD + r*QK_PITCH + d] = f2bf(val * SCALE);
                    } else if (which == 1) {
                        if (r < NTOK) k_s[hh*Q_HEAD + r*QK_PITCH + d] = f2bf(val);
                    } else {
                        // v^T: col j=r; pad cols 49..63 get exact zeros (kills stale-LDS NaN risk)
                        v_t[hh*VT_HEAD + d*VT_PITCH + r] = (r < NTOK) ? f2bf(val) : (short)0;
                    }
                }
            }
        }
    }
    __syncthreads();

    // ============ Phase 2 (MFMA attention, wave = head) ============
    const int h  = w;
    const int mw = b & 63;                       // mask window = b % 64
    const float* mrow = mask + (size_t)mw * (NTOK*NTOK);

    // ---- S = (q*scale) @ k^T : 4x4 tiles of 16x16, K=32 (one MFMA step) ----
    f32x4 s[4][4];
    #pragma unroll
    for (int m = 0; m < 4; ++m)
        #pragma unroll
        for (int n = 0; n < 4; ++n)
            s[m][n] = (f32x4){0.f, 0.f, 0.f, 0.f};
    {
        bf16x8 qa[4], kb[4];
        #pragma unroll
        for (int m = 0; m < 4; ++m) {
            const int r = 16*m + lrow;
            const int ii = (r < NTOK) ? r : (NTOK-1);   // clamp: dup rows, never consumed
            qa[m] = *reinterpret_cast<const bf16x8*>(q_s + h*Q_HEAD + ii*QK_PITCH + 8*kgrp);
        }
        #pragma unroll
        for (int n = 0; n < 4; ++n) {
            const int r = 16*n + lrow;
            const int jj = (r < NTOK) ? r : (NTOK-1);
            kb[n] = *reinterpret_cast<const bf16x8*>(k_s + h*Q_HEAD + jj*QK_PITCH + 8*kgrp);
        }
        #pragma unroll
        for (int m = 0; m < 4; ++m)
            #pragma unroll
            for (int n = 0; n < 4; ++n)
                s[m][n] = __builtin_amdgcn_mfma_f32_16x16x32_bf16(qa[m], kb[n], s[m][n], 0, 0, 0);
    }

    // ---- + relative-position bias + shifted-window mask (j = 16n+lrow: coalesced) ----
    #pragma unroll
    for (int m = 0; m < 4; ++m) {
        #pragma unroll
        for (int q = 0; q < 4; ++q) {
            const int i = 16*m + 4*kgrp + q;
            #pragma unroll
            for (int n = 0; n < 4; ++n) {
                const int j = 16*n + lrow;
                if (i < NTOK && j < NTOK) {
                    const int ridx = rel_index[i*NTOK + j];
                    s[m][n][q] += bias_table[ridx*NHEAD + h] + mrow[i*NTOK + j];
                } else {
                    s[m][n][q] = -1e30f;   // finite "-inf": exp underflows to exactly 0
                }
            }
        }
    }

    // ---- in-register softmax over j: 4 n-regs + 4 shfl_xor steps (16 indep chains) ----
    #pragma unroll
    for (int m = 0; m < 4; ++m) {
        #pragma unroll
        for (int q = 0; q < 4; ++q) {
            float mx = fmaxf(fmaxf(s[m][0][q], s[m][1][q]), fmaxf(s[m][2][q], s[m][3][q]));
            mx = fmaxf(mx, __shfl_xor(mx, 1));
            mx = fmaxf(mx, __shfl_xor(mx, 2));
            mx = fmaxf(mx, __shfl_xor(mx, 4));
            mx = fmaxf(mx, __shfl_xor(mx, 8));
            float sum = 0.f;
            #pragma unroll
            for (int n = 0; n < 4; ++n) {
                const float e = __expf(s[m][n][q] - mx);
                s[m][n][q] = e;
                sum += e;
            }
            sum += __shfl_xor(sum, 1);
            sum += __shfl_xor(sum, 2);
            sum += __shfl_xor(sum, 4);
            sum += __shfl_xor(sum, 8);
            const float inv = __builtin_amdgcn_rcpf(sum);
            const int i = 16*m + 4*kgrp + q;
            if (i < NTOK) {
                #pragma unroll
                for (int n = 0; n < 4; ++n)
                    p_s[h*P_HEAD + i*P_PITCH + 16*n + lrow] = f2bf(s[m][n][q] * inv);
            }
        }
    }
    // (same-wave p_s write->read: compiler inserts lgkmcnt wait)

    // ---- O = P @ V : A=P rows i, B=v_t rows d, K=j in 2 steps of 32 ----
    f32x4 o[4][2];
    #pragma unroll
    for (int m = 0; m < 4; ++m)
        #pragma unroll
        for (int n = 0; n < 2; ++n)
            o[m][n] = (f32x4){0.f, 0.f, 0.f, 0.f};
    #pragma unroll
    for (int ks = 0; ks < 2; ++ks) {
        bf16x8 pa[4], vb[2];
        #pragma unroll
        for (int m = 0; m < 4; ++m) {
            const int r = 16*m + lrow;
            const int ii = (r < NTOK) ? r : (NTOK-1);
            pa[m] = *reinterpret_cast<const bf16x8*>(p_s + h*P_HEAD + ii*P_PITCH + 32*ks + 8*kgrp);
        }
        #pragma unroll
        for (int n = 0; n < 2; ++n) {
            const int d = 16*n + lrow;   // 0..31 exact
            vb[n] = *reinterpret_cast<const bf16x8*>(v_t + h*VT_HEAD + d*VT_PITCH + 32*ks + 8*kgrp);
        }
        #pragma unroll
        for (int m = 0; m < 4; ++m)
            #pragma unroll
            for (int n = 0; n < 2; ++n)
                o[m][n] = __builtin_amdgcn_mfma_f32_16x16x32_bf16(pa[m], vb[n], o[m][n], 0, 0, 0);
    }

    __syncthreads();   // all waves done reading p_s before o_s (alias) is written

    #pragma unroll
    for (int n = 0; n < 2; ++n) {
        #pragma unroll
        for (int m = 0; m < 4; ++m) {
            #pragma unroll
            for (int q = 0; q < 4; ++q) {
                const int i = 16*m + 4*kgrp + q;
                if (i < NTOK)
                    o_s[i*OPITCH + h*HDIM + 16*n + lrow] = f2bf(o[m][n][q]);
            }
        }
    }
    __syncthreads();

    // ============ Phase 3 (MFMA, validated r6): out = o @ proj_w^T + proj_b ============
    {
        f32x4 pacc[4][2];
        #pragma unroll
        for (int m = 0; m < 4; ++m)
            #pragma unroll
            for (int n = 0; n < 2; ++n)
                pacc[m][n] = (f32x4){0.f, 0.f, 0.f, 0.f};

        #pragma unroll
        for (int ks = 0; ks < 4; ++ks) {
            const int k0 = 32*ks + 8*kgrp;
            bf16x8 afr[4];
            #pragma unroll
            for (int m = 0; m < 4; ++m) {
                const int r = 16*m + lrow;
                const int rr = (r < NTOK) ? r : 0;
                afr[m] = *reinterpret_cast<const bf16x8*>(o_s + rr*OPITCH + k0);
            }
            bf16x8 bfr[2];
            #pragma unroll
            for (int n = 0; n < 2; ++n) {
                const int c = 32*w + 16*n + lrow;
                float4 lo = *reinterpret_cast<const float4*>(proj_w + c*DIMC + k0);
                float4 hi = *reinterpret_cast<const float4*>(proj_w + c*DIMC + k0 + 4);
                bfr[n] = cvt8(lo, hi);
            }
            #pragma unroll
            for (int m = 0; m < 4; ++m)
                #pragma unroll
                for (int n = 0; n < 2; ++n)
                    pacc[m][n] = __builtin_amdgcn_mfma_f32_16x16x32_bf16(
                                     afr[m], bfr[n], pacc[m][n], 0, 0, 0);
        }

        float* ob = out + (size_t)b * (NTOK * DIMC);
        #pragma unroll
        for (int n = 0; n < 2; ++n) {
            const int c    = 32*w + 16*n + lrow;
            const float bi = proj_b[c];
            #pragma unroll
            for (int m = 0; m < 4; ++m) {
                #pragma unroll
                for (int q = 0; q < 4; ++q) {
                    const int r = 16*m + 4*kgrp + q;
                    if (r < NTOK) ob[r*DIMC + c] = pacc[m][n][q] + bi;
                }
            }
        }
    }
}

extern "C" void kernel_launch(void* const* d_in, const int* in_sizes, int n_in,
                              void* d_out, int out_size, void* d_ws, size_t ws_size,
                              hipStream_t stream) {
    const float* x      = (const float*)d_in[0];
    const float* mask   = (const float*)d_in[1];
    const float* qkv_w  = (const float*)d_in[2];
    const float* qkv_b  = (const float*)d_in[3];
    const float* proj_w = (const float*)d_in[4];
    const float* proj_b = (const float*)d_in[5];
    const float* tbl    = (const float*)d_in[6];
    const int*   ridx   = (const int*)d_in[7];
    float* out = (float*)d_out;

    const int B = in_sizes[0] / (NTOK * DIMC);   // 4096 windows
    const size_t shmem = 78016;                  // bytes (>64KB: needs attr)

    hipFuncSetAttribute(reinterpret_cast<const void*>(winattn_fused),
                        hipFuncAttributeMaxDynamicSharedMemorySize, (int)shmem);
    winattn_fused<<<B, 256, shmem, stream>>>(x, mask, qkv_w, qkv_b,
                                             proj_w, proj_b, tbl, ridx, out);
}